// Round 2
// baseline (330.010 us; speedup 1.0000x reference)
//
#include <hip/hip_runtime.h>
#include <math.h>

#define SS 512
#define DD 128
#define HH 4
#define DHH 32
#define DFF 512
#define E_EDGES 261632   // S*S - S

__device__ __forceinline__ float gelu_f(float v) {
    return 0.5f * v * (1.0f + erff(v * 0.70710678118654752f));
}

// ---------------- embedding + positional encoding ----------------
__global__ __launch_bounds__(128) void k_embed(const int* __restrict__ tok,
                                               const float* __restrict__ emb,
                                               float* __restrict__ x) {
    int s = blockIdx.x;
    int d = threadIdx.x;
    float v = emb[(size_t)tok[s] * DD + d];
    int i2 = (d >> 1) << 1;                       // 2*(d/2)
    float div = expf(-(float)i2 * (9.210340371976184f / 128.0f));
    float arg = (float)s * div;
    v += (d & 1) ? cosf(arg) : sinf(arg);
    x[s * DD + d] = v;
}

// ---------------- qkv projection: x[512,128] @ W[128,384] + b ----------------
__global__ __launch_bounds__(384) void k_qkv(const float* __restrict__ x,
                                             const float* __restrict__ W,
                                             const float* __restrict__ b,
                                             float* __restrict__ qkv) {
    __shared__ float xs[4][DD];
    int r0 = blockIdx.x * 4;
    int c = threadIdx.x;
    for (int i = threadIdx.x; i < 4 * DD; i += 384)
        xs[i >> 7][i & 127] = x[(r0 + (i >> 7)) * DD + (i & 127)];
    __syncthreads();
    float a0 = 0, a1 = 0, a2 = 0, a3 = 0;
    for (int d = 0; d < DD; ++d) {
        float w = W[d * 384 + c];
        a0 += xs[0][d] * w; a1 += xs[1][d] * w;
        a2 += xs[2][d] * w; a3 += xs[3][d] * w;
    }
    float bb = b[c];
    qkv[(r0 + 0) * 384 + c] = a0 + bb;
    qkv[(r0 + 1) * 384 + c] = a1 + bb;
    qkv[(r0 + 2) * 384 + c] = a2 + bb;
    qkv[(r0 + 3) * 384 + c] = a3 + bb;
}

// ---------------- attention: one block per query row, one wave per head ----------------
__global__ __launch_bounds__(256) void k_attn(const float* __restrict__ qkv,
                                              float* __restrict__ o) {
    int qi = blockIdx.x;
    int h = threadIdx.x >> 6;
    int lane = threadIdx.x & 63;
    __shared__ float sq[DD];
    __shared__ float ps[HH][SS];
    if (threadIdx.x < DD) sq[threadIdx.x] = qkv[qi * 384 + threadIdx.x];
    __syncthreads();
    const float scale = 0.17677669529663687f;     // 1/sqrt(32)
    float sc[8];
    float m = -1e30f;
    for (int kk = 0; kk < 8; ++kk) {
        int ki = kk * 64 + lane;
        const float* kp = qkv + ki * 384 + 128 + h * DHH;
        float acc = 0.f;
        #pragma unroll
        for (int d = 0; d < DHH; ++d) acc += sq[h * DHH + d] * kp[d];
        acc *= scale;
        sc[kk] = acc;
        m = fmaxf(m, acc);
    }
    for (int off = 32; off; off >>= 1) m = fmaxf(m, __shfl_xor(m, off));
    float sum = 0.f;
    for (int kk = 0; kk < 8; ++kk) { sc[kk] = expf(sc[kk] - m); sum += sc[kk]; }
    for (int off = 32; off; off >>= 1) sum += __shfl_xor(sum, off);
    float inv = 1.0f / sum;
    for (int kk = 0; kk < 8; ++kk) ps[h][kk * 64 + lane] = sc[kk] * inv;
    __syncthreads();
    int d = lane & 31, hh2 = lane >> 5;
    float acc = 0.f;
    for (int i = 0; i < 256; ++i) {
        int ki = hh2 * 256 + i;
        acc += ps[h][ki] * qkv[ki * 384 + 256 + h * DHH + d];
    }
    acc += __shfl_down(acc, 32);
    if (lane < 32) o[qi * DD + h * DHH + d] = acc;
}

// ---------------- o @ Wo + bo + residual -> LayerNorm (in-place on x) ----------------
__global__ __launch_bounds__(128) void k_proj_ln(const float* __restrict__ o,
                                                 const float* __restrict__ W,
                                                 const float* __restrict__ b,
                                                 const float* __restrict__ g,
                                                 const float* __restrict__ be,
                                                 float* __restrict__ x) {
    int row = blockIdx.x;
    int c = threadIdx.x;
    __shared__ float os[DD];
    __shared__ float red[2];
    os[c] = o[row * DD + c];
    __syncthreads();
    float acc = 0.f;
    for (int d = 0; d < DD; ++d) acc += os[d] * W[d * DD + c];
    float val = x[row * DD + c] + acc + b[c];
    float sum = val;
    for (int off = 32; off; off >>= 1) sum += __shfl_xor(sum, off);
    if ((threadIdx.x & 63) == 0) red[threadIdx.x >> 6] = sum;
    __syncthreads();
    float mean = (red[0] + red[1]) * (1.0f / 128.0f);
    float dv = val - mean;
    float sq = dv * dv;
    for (int off = 32; off; off >>= 1) sq += __shfl_xor(sq, off);
    __syncthreads();
    if ((threadIdx.x & 63) == 0) red[threadIdx.x >> 6] = sq;
    __syncthreads();
    float var = (red[0] + red[1]) * (1.0f / 128.0f);
    float outv = dv * rsqrtf(var + 1e-5f) * g[c] + be[c];
    x[row * DD + c] = outv;
}

// ---------------- FFN1: gelu(x @ Wff1 + b) -> hbuf[512,512] ----------------
__global__ __launch_bounds__(512) void k_ffn1(const float* __restrict__ x,
                                              const float* __restrict__ W,
                                              const float* __restrict__ b,
                                              float* __restrict__ hbuf) {
    __shared__ float xs[4][DD];
    int r0 = blockIdx.x * 4;
    int c = threadIdx.x;
    for (int i = threadIdx.x; i < 4 * DD; i += 512)
        xs[i >> 7][i & 127] = x[(r0 + (i >> 7)) * DD + (i & 127)];
    __syncthreads();
    float a0 = 0, a1 = 0, a2 = 0, a3 = 0;
    for (int d = 0; d < DD; ++d) {
        float w = W[d * DFF + c];
        a0 += xs[0][d] * w; a1 += xs[1][d] * w;
        a2 += xs[2][d] * w; a3 += xs[3][d] * w;
    }
    float bb = b[c];
    hbuf[(r0 + 0) * DFF + c] = gelu_f(a0 + bb);
    hbuf[(r0 + 1) * DFF + c] = gelu_f(a1 + bb);
    hbuf[(r0 + 2) * DFF + c] = gelu_f(a2 + bb);
    hbuf[(r0 + 3) * DFF + c] = gelu_f(a3 + bb);
}

// ---------------- FFN2 + residual -> LayerNorm (in-place on x) ----------------
__global__ __launch_bounds__(128) void k_ffn2_ln(const float* __restrict__ hbuf,
                                                 const float* __restrict__ W,
                                                 const float* __restrict__ b,
                                                 const float* __restrict__ g,
                                                 const float* __restrict__ be,
                                                 float* __restrict__ x) {
    int row = blockIdx.x;
    int c = threadIdx.x;
    __shared__ float hs[DFF];
    __shared__ float red[2];
    for (int i = c; i < DFF; i += 128) hs[i] = hbuf[row * DFF + i];
    __syncthreads();
    float acc = 0.f;
    for (int d = 0; d < DFF; ++d) acc += hs[d] * W[d * DD + c];
    float val = x[row * DD + c] + acc + b[c];
    float sum = val;
    for (int off = 32; off; off >>= 1) sum += __shfl_xor(sum, off);
    if ((threadIdx.x & 63) == 0) red[threadIdx.x >> 6] = sum;
    __syncthreads();
    float mean = (red[0] + red[1]) * (1.0f / 128.0f);
    float dv = val - mean;
    float sq = dv * dv;
    for (int off = 32; off; off >>= 1) sq += __shfl_xor(sq, off);
    __syncthreads();
    if ((threadIdx.x & 63) == 0) red[threadIdx.x >> 6] = sq;
    __syncthreads();
    float var = (red[0] + red[1]) * (1.0f / 128.0f);
    float outv = dv * rsqrtf(var + 1e-5f) * g[c] + be[c];
    x[row * DD + c] = outv;
}

// ---------------- node features + per-node edge-MLP partials ----------------
// columns: [0,64) node_W | [64,192) sc_W1 src | [192,320) sc_W1 tgt
//          [320,384) te_W src | [384,448) te_W tgt
__global__ __launch_bounds__(448) void k_node_pre(const float* __restrict__ x,
                                                  const float* __restrict__ nodeW,
                                                  const float* __restrict__ nodeb,
                                                  const float* __restrict__ scW1,
                                                  const float* __restrict__ scb1,
                                                  const float* __restrict__ teW,
                                                  const float* __restrict__ teb,
                                                  float* __restrict__ out_node,
                                                  float* __restrict__ As,
                                                  float* __restrict__ At,
                                                  float* __restrict__ Bs,
                                                  float* __restrict__ Bt) {
    __shared__ float xs[4][DD];
    int r0 = blockIdx.x * 4;
    for (int i = threadIdx.x; i < 4 * DD; i += 448)
        xs[i >> 7][i & 127] = x[(r0 + (i >> 7)) * DD + (i & 127)];
    __syncthreads();
    int c = threadIdx.x;
    const float* wp;
    int ldw;
    if (c < 64)       { wp = nodeW + c;                ldw = 64;  }
    else if (c < 192) { wp = scW1 + (c - 64);          ldw = 128; }
    else if (c < 320) { wp = scW1 + 128 * 128 + (c - 192); ldw = 128; }
    else if (c < 384) { wp = teW + (c - 320);          ldw = 64;  }
    else              { wp = teW + 128 * 64 + (c - 384);   ldw = 64;  }
    float a[4] = {0, 0, 0, 0};
    for (int d = 0; d < DD; ++d) {
        float w = wp[d * ldw];
        a[0] += xs[0][d] * w; a[1] += xs[1][d] * w;
        a[2] += xs[2][d] * w; a[3] += xs[3][d] * w;
    }
    #pragma unroll
    for (int r = 0; r < 4; ++r) {
        int row = r0 + r;
        float v = a[r];
        if (c < 64)       out_node[row * 64 + c] = v + nodeb[c];
        else if (c < 192) As[row * 128 + (c - 64)] = v + scb1[c - 64];   // fold sc_b1
        else if (c < 320) At[row * 128 + (c - 192)] = v;
        else if (c < 384) Bs[row * 64 + (c - 320)] = v + teb[c - 320];   // fold te_b
        else              Bt[row * 64 + (c - 384)] = v;
    }
}

// ---------------- edge kernel: one wave per edge ----------------
__global__ __launch_bounds__(256) void k_edges(const float* __restrict__ As,
                                               const float* __restrict__ At,
                                               const float* __restrict__ Bs,
                                               const float* __restrict__ Bt,
                                               const float* __restrict__ scW1,
                                               const float* __restrict__ scW2,
                                               const float* __restrict__ scb2p,
                                               const float* __restrict__ teW,
                                               const float* __restrict__ u,
                                               float* __restrict__ out_feat,
                                               float* __restrict__ out_gate) {
    int s = blockIdx.x;
    int half = blockIdx.y;
    __shared__ float lAs[128], lap[128], lw2[128], lBs[64], lbp[64];
    int tid = threadIdx.x;
    if (tid < 128) {
        lAs[tid] = As[s * 128 + tid];
        lap[tid] = scW1[256 * 128 + tid];
        lw2[tid] = scW2[tid];
    } else if (tid < 192) {
        int j = tid - 128;
        lBs[j] = Bs[s * 64 + j];
        lbp[j] = teW[256 * 64 + j];
    }
    __syncthreads();
    float scb2 = scb2p[0];
    int w = tid >> 6, lane = tid & 63;
    for (int iter = 0; iter < 64; ++iter) {
        int idx = half * 256 + iter * 4 + w;
        if (idx >= 511) continue;                  // uniform within wave
        int t = idx + (idx >= s);
        int e = s * 511 + idx;
        float pd = (float)(s - t) * (1.0f / 512.0f);
        int j = lane;
        float a0 = lAs[j]      + At[t * 128 + j]      + pd * lap[j];
        float a1 = lAs[j + 64] + At[t * 128 + 64 + j] + pd * lap[j + 64];
        float part = gelu_f(a0) * lw2[j] + gelu_f(a1) * lw2[j + 64];
        for (int off = 32; off; off >>= 1) part += __shfl_xor(part, off);
        float logit = part + scb2;
        float uu = u[e];
        uu = fminf(fmaxf(uu, 1e-8f), 1.0f - 1e-8f);
        float gn = -logf(-logf(uu));
        float gate = 1.0f / (1.0f + expf(-(logit + gn)));
        float f = (lBs[j] + Bt[t * 64 + j] + pd * lbp[j]) * gate;
        out_feat[(size_t)e * 64 + j] = f;
        if (lane == 0) out_gate[e] = gate;
    }
}

// ---------------- edge_index as float ----------------
__global__ __launch_bounds__(256) void k_eidx(float* __restrict__ out_ei) {
    int i = blockIdx.x * 256 + threadIdx.x;
    if (i >= 2 * E_EDGES) return;
    int which = (i >= E_EDGES);
    int e = which ? i - E_EDGES : i;
    int s = e / 511;
    int idx = e - s * 511;
    int t = idx + (idx >= s);
    out_ei[i] = (float)(which ? t : s);
}

extern "C" void kernel_launch(void* const* d_in, const int* in_sizes, int n_in,
                              void* d_out, int out_size, void* d_ws, size_t ws_size,
                              hipStream_t stream) {
    const int*   tok   = (const int*)d_in[0];
    const float* u     = (const float*)d_in[1];
    const float* emb   = (const float*)d_in[2];
    const float* Wqkv  = (const float*)d_in[3];
    const float* bqkv  = (const float*)d_in[4];
    const float* Wo    = (const float*)d_in[5];
    const float* bo    = (const float*)d_in[6];
    const float* ln1g  = (const float*)d_in[7];
    const float* ln1b  = (const float*)d_in[8];
    const float* Wff1  = (const float*)d_in[9];
    const float* bff1  = (const float*)d_in[10];
    const float* Wff2  = (const float*)d_in[11];
    const float* bff2  = (const float*)d_in[12];
    const float* ln2g  = (const float*)d_in[13];
    const float* ln2b  = (const float*)d_in[14];
    const float* nodeW = (const float*)d_in[15];
    const float* nodeb = (const float*)d_in[16];
    const float* scW1  = (const float*)d_in[17];
    const float* scb1  = (const float*)d_in[18];
    const float* scW2  = (const float*)d_in[19];
    const float* scb2  = (const float*)d_in[20];
    const float* teW   = (const float*)d_in[21];
    const float* teb   = (const float*)d_in[22];

    float* out      = (float*)d_out;
    float* out_node = out;                                    // [512,64]
    float* out_feat = out + 512 * 64;                         // [E,64]
    float* out_ei   = out_feat + (size_t)E_EDGES * 64;        // [2,E]
    float* out_gate = out_ei + 2 * (size_t)E_EDGES;           // [E]

    float* ws   = (float*)d_ws;
    float* x    = ws;
    float* qkv  = x + 512 * 128;
    float* o    = qkv + 512 * 384;
    float* hbuf = o + 512 * 128;
    float* As   = hbuf + 512 * 512;
    float* At   = As + 512 * 128;
    float* Bs   = At + 512 * 128;
    float* Bt   = Bs + 512 * 64;

    k_embed<<<dim3(512), dim3(128), 0, stream>>>(tok, emb, x);
    for (int l = 0; l < 2; ++l) {
        k_qkv<<<dim3(128), dim3(384), 0, stream>>>(x, Wqkv + l * 128 * 384, bqkv + l * 384, qkv);
        k_attn<<<dim3(512), dim3(256), 0, stream>>>(qkv, o);
        k_proj_ln<<<dim3(512), dim3(128), 0, stream>>>(o, Wo + l * 128 * 128, bo + l * 128,
                                                       ln1g + l * 128, ln1b + l * 128, x);
        k_ffn1<<<dim3(128), dim3(512), 0, stream>>>(x, Wff1 + l * 128 * 512, bff1 + l * 512, hbuf);
        k_ffn2_ln<<<dim3(512), dim3(128), 0, stream>>>(hbuf, Wff2 + l * 512 * 128, bff2 + l * 128,
                                                       ln2g + l * 128, ln2b + l * 128, x);
    }
    k_node_pre<<<dim3(128), dim3(448), 0, stream>>>(x, nodeW, nodeb, scW1, scb1, teW, teb,
                                                    out_node, As, At, Bs, Bt);
    k_edges<<<dim3(512, 2), dim3(256), 0, stream>>>(As, At, Bs, Bt, scW1, scW2, scb2, teW, u,
                                                    out_feat, out_gate);
    k_eidx<<<dim3((2 * E_EDGES + 255) / 256), dim3(256), 0, stream>>>(out_ei);
}

// Round 3
// 287.742 us; speedup vs baseline: 1.1469x; 1.1469x over previous
//
#include <hip/hip_runtime.h>
#include <math.h>

#define SS 512
#define DD 128
#define HH 4
#define DHH 32
#define DFF 512
#define E_EDGES 261632   // S*S - S

// exact gelu (backbone — cheap there, keeps node_features bit-comparable)
__device__ __forceinline__ float gelu_f(float v) {
    return 0.5f * v * (1.0f + erff(v * 0.70710678118654752f));
}
// fast gelu (edge kernel): x * sigmoid(1.5957691*(x + 0.044715 x^3))
// max abs error vs exact ~1e-3; after w2-dot (std 0.02) -> dlogit ~2e-4, far below 2% thresholds
__device__ __forceinline__ float fgelu(float x) {
    float x2 = x * x;
    float z = x * fmaf(0.044715f, x2, 1.0f) * -1.5957691216057308f;
    float e = __expf(z);
    return x * __builtin_amdgcn_rcpf(1.0f + e);
}

// ---------------- embedding + positional encoding ----------------
__global__ __launch_bounds__(128) void k_embed(const int* __restrict__ tok,
                                               const float* __restrict__ emb,
                                               float* __restrict__ x) {
    int s = blockIdx.x;
    int d = threadIdx.x;
    float v = emb[(size_t)tok[s] * DD + d];
    int i2 = (d >> 1) << 1;
    float div = expf(-(float)i2 * (9.210340371976184f / 128.0f));
    float arg = (float)s * div;
    v += (d & 1) ? cosf(arg) : sinf(arg);
    x[s * DD + d] = v;
}

// ---------------- qkv projection ----------------
__global__ __launch_bounds__(384) void k_qkv(const float* __restrict__ x,
                                             const float* __restrict__ W,
                                             const float* __restrict__ b,
                                             float* __restrict__ qkv) {
    __shared__ float xs[4][DD];
    int r0 = blockIdx.x * 4;
    int c = threadIdx.x;
    for (int i = threadIdx.x; i < 4 * DD; i += 384)
        xs[i >> 7][i & 127] = x[(r0 + (i >> 7)) * DD + (i & 127)];
    __syncthreads();
    float a0 = 0, a1 = 0, a2 = 0, a3 = 0;
    for (int d = 0; d < DD; ++d) {
        float w = W[d * 384 + c];
        a0 += xs[0][d] * w; a1 += xs[1][d] * w;
        a2 += xs[2][d] * w; a3 += xs[3][d] * w;
    }
    float bb = b[c];
    qkv[(r0 + 0) * 384 + c] = a0 + bb;
    qkv[(r0 + 1) * 384 + c] = a1 + bb;
    qkv[(r0 + 2) * 384 + c] = a2 + bb;
    qkv[(r0 + 3) * 384 + c] = a3 + bb;
}

// ---------------- attention: block per query row; K staged in LDS tiles ----------------
__global__ __launch_bounds__(256) void k_attn(const float* __restrict__ qkv,
                                              float* __restrict__ o) {
    int qi = blockIdx.x;
    int tid = threadIdx.x;
    int h = tid >> 6, lane = tid & 63;
    __shared__ float sq[DD];
    __shared__ float ps[HH][SS];
    __shared__ float tile[64 * 129];
    if (tid < DD) sq[tid] = qkv[qi * 384 + tid];
    const float scale = 0.17677669529663687f;     // 1/sqrt(32)
    float sc[8];
    float m = -1e30f;
    for (int kk = 0; kk < 8; ++kk) {
        __syncthreads();                           // protect tile (and sq on first iter)
        for (int i = tid * 4; i < 64 * 128; i += 1024) {
            int r = i >> 7, c = i & 127;
            const float4 v = *reinterpret_cast<const float4*>(&qkv[(kk * 64 + r) * 384 + 128 + c]);
            tile[r * 129 + c + 0] = v.x;
            tile[r * 129 + c + 1] = v.y;
            tile[r * 129 + c + 2] = v.z;
            tile[r * 129 + c + 3] = v.w;
        }
        __syncthreads();
        float acc = 0.f;
        #pragma unroll
        for (int d = 0; d < DHH; ++d)
            acc += sq[h * DHH + d] * tile[lane * 129 + h * DHH + d];
        acc *= scale;
        sc[kk] = acc;
        m = fmaxf(m, acc);
    }
    for (int off = 32; off; off >>= 1) m = fmaxf(m, __shfl_xor(m, off));
    float sum = 0.f;
    for (int kk = 0; kk < 8; ++kk) { sc[kk] = __expf(sc[kk] - m); sum += sc[kk]; }
    for (int off = 32; off; off >>= 1) sum += __shfl_xor(sum, off);
    float inv = 1.0f / sum;
    for (int kk = 0; kk < 8; ++kk) ps[h][kk * 64 + lane] = sc[kk] * inv;
    __syncthreads();
    int d = lane & 31, hh2 = lane >> 5;
    float acc = 0.f;
    for (int i = 0; i < 256; ++i) {
        int ki = hh2 * 256 + i;
        acc += ps[h][ki] * qkv[ki * 384 + 256 + h * DHH + d];
    }
    acc += __shfl_down(acc, 32);
    if (lane < 32) o[qi * DD + h * DHH + d] = acc;
}

// ---------------- fused layer tail: proj+LN1 -> FFN1 -> FFN2+LN2 (2 rows/block) ----------------
__global__ __launch_bounds__(256) void k_tail(const float* __restrict__ o,
                                              const float* __restrict__ Wo,
                                              const float* __restrict__ bo,
                                              const float* __restrict__ g1,
                                              const float* __restrict__ b1,
                                              const float* __restrict__ W1,
                                              const float* __restrict__ bf1,
                                              const float* __restrict__ W2,
                                              const float* __restrict__ bf2,
                                              const float* __restrict__ g2,
                                              const float* __restrict__ b2,
                                              float* __restrict__ x) {
    int r0 = blockIdx.x * 2;
    int tid = threadIdx.x;
    int grp = tid >> 7, c = tid & 127;
    int wig = (tid >> 6) & 1;
    __shared__ float osr[2][DD];
    __shared__ float x1[2][DD];
    __shared__ float hh[2][DFF];
    __shared__ float red[2][2];
    osr[grp][c] = o[(r0 + grp) * DD + c];
    float xres = x[(r0 + grp) * DD + c];
    __syncthreads();
    float acc = 0.f;
    for (int d = 0; d < DD; ++d) acc += osr[grp][d] * Wo[d * DD + c];
    float val = xres + acc + bo[c];
    // LN1
    float sum = val;
    for (int off = 32; off; off >>= 1) sum += __shfl_xor(sum, off);
    if ((tid & 63) == 0) red[grp][wig] = sum;
    __syncthreads();
    float mean = (red[grp][0] + red[grp][1]) * (1.0f / 128.0f);
    float dv = val - mean;
    float sq = dv * dv;
    for (int off = 32; off; off >>= 1) sq += __shfl_xor(sq, off);
    __syncthreads();
    if ((tid & 63) == 0) red[grp][wig] = sq;
    __syncthreads();
    float var = (red[grp][0] + red[grp][1]) * (1.0f / 128.0f);
    float xv = dv * rsqrtf(var + 1e-5f) * g1[c] + b1[c];
    x1[grp][c] = xv;
    __syncthreads();
    // FFN1: thread -> cols (tid, tid+256) x rows (0,1)
    {
        int c0 = tid, c1 = tid + 256;
        float s00 = 0, s01 = 0, s10 = 0, s11 = 0;
        for (int d = 0; d < DD; ++d) {
            float xa = x1[0][d], xb = x1[1][d];
            float w0 = W1[d * DFF + c0], w1 = W1[d * DFF + c1];
            s00 = fmaf(xa, w0, s00); s10 = fmaf(xb, w0, s10);
            s01 = fmaf(xa, w1, s01); s11 = fmaf(xb, w1, s11);
        }
        hh[0][c0] = gelu_f(s00 + bf1[c0]);
        hh[1][c0] = gelu_f(s10 + bf1[c0]);
        hh[0][c1] = gelu_f(s01 + bf1[c1]);
        hh[1][c1] = gelu_f(s11 + bf1[c1]);
    }
    __syncthreads();
    // FFN2 + LN2
    float acc2 = 0.f;
    for (int d = 0; d < DFF; ++d) acc2 += hh[grp][d] * W2[d * DD + c];
    float val2 = x1[grp][c] + acc2 + bf2[c];
    float sum2 = val2;
    for (int off = 32; off; off >>= 1) sum2 += __shfl_xor(sum2, off);
    if ((tid & 63) == 0) red[grp][wig] = sum2;
    __syncthreads();
    float mean2 = (red[grp][0] + red[grp][1]) * (1.0f / 128.0f);
    float dv2 = val2 - mean2;
    float sq2 = dv2 * dv2;
    for (int off = 32; off; off >>= 1) sq2 += __shfl_xor(sq2, off);
    __syncthreads();
    if ((tid & 63) == 0) red[grp][wig] = sq2;
    __syncthreads();
    float var2 = (red[grp][0] + red[grp][1]) * (1.0f / 128.0f);
    x[(r0 + grp) * DD + c] = dv2 * rsqrtf(var2 + 1e-5f) * g2[c] + b2[c];
}

// ---------------- node features + per-node edge-MLP partials (At packed float2) ----------------
__global__ __launch_bounds__(448) void k_node_pre(const float* __restrict__ x,
                                                  const float* __restrict__ nodeW,
                                                  const float* __restrict__ nodeb,
                                                  const float* __restrict__ scW1,
                                                  const float* __restrict__ scb1,
                                                  const float* __restrict__ teW,
                                                  const float* __restrict__ teb,
                                                  float* __restrict__ out_node,
                                                  float* __restrict__ As,
                                                  float* __restrict__ At2,
                                                  float* __restrict__ Bs,
                                                  float* __restrict__ Bt) {
    __shared__ float xs[4][DD];
    int r0 = blockIdx.x * 4;
    for (int i = threadIdx.x; i < 4 * DD; i += 448)
        xs[i >> 7][i & 127] = x[(r0 + (i >> 7)) * DD + (i & 127)];
    __syncthreads();
    int c = threadIdx.x;
    const float* wp;
    int ldw;
    if (c < 64)       { wp = nodeW + c;                    ldw = 64;  }
    else if (c < 192) { wp = scW1 + (c - 64);              ldw = 128; }
    else if (c < 320) { wp = scW1 + 128 * 128 + (c - 192); ldw = 128; }
    else if (c < 384) { wp = teW + (c - 320);              ldw = 64;  }
    else              { wp = teW + 128 * 64 + (c - 384);   ldw = 64;  }
    float a[4] = {0, 0, 0, 0};
    for (int d = 0; d < DD; ++d) {
        float w = wp[d * ldw];
        a[0] += xs[0][d] * w; a[1] += xs[1][d] * w;
        a[2] += xs[2][d] * w; a[3] += xs[3][d] * w;
    }
    #pragma unroll
    for (int r = 0; r < 4; ++r) {
        int row = r0 + r;
        float v = a[r];
        if (c < 64)       out_node[row * 64 + c] = v + nodeb[c];
        else if (c < 192) As[row * 128 + (c - 64)] = v + scb1[c - 64];
        else if (c < 320) {
            int j = c - 192;                           // pack (j, j+64) adjacent
            At2[row * 128 + ((j & 63) * 2 + (j >> 6))] = v;
        }
        else if (c < 384) Bs[row * 64 + (c - 320)] = v + teb[c - 320];
        else              Bt[row * 64 + (c - 384)] = v;
    }
}

// ---------------- static: edge_index + (-log u) precompute ----------------
__global__ __launch_bounds__(256) void k_estatic(const float* __restrict__ u,
                                                 float* __restrict__ nl,
                                                 float* __restrict__ out_ei) {
    int e = blockIdx.x * 256 + threadIdx.x;
    if (e >= E_EDGES) return;
    int s = e / 511;
    int idx = e - s * 511;
    int t = idx + (idx >= s);
    out_ei[e] = (float)s;
    out_ei[E_EDGES + e] = (float)t;
    float uu = fminf(fmaxf(u[e], 1e-8f), 1.0f - 1e-8f);
    nl[e] = -__logf(uu);   // exp(-gumbel_noise); gate = 1/(1 + nl*exp(-logit))
}

// ---------------- edge kernel: one wave per edge ----------------
__global__ __launch_bounds__(256) void k_edges(const float* __restrict__ As,
                                               const float* __restrict__ At2,
                                               const float* __restrict__ Bs,
                                               const float* __restrict__ Bt,
                                               const float* __restrict__ scW1,
                                               const float* __restrict__ scW2,
                                               const float* __restrict__ scb2p,
                                               const float* __restrict__ teW,
                                               const float* __restrict__ nl,
                                               float* __restrict__ out_feat,
                                               float* __restrict__ out_gate) {
    int s = blockIdx.x;
    int seg = blockIdx.y;                          // 0..7, 64 edges each
    __shared__ float lAs[128], lap[128], lw2[128], lBs[64], lbp[64];
    int tid = threadIdx.x;
    if (tid < 128) {
        lAs[tid] = As[s * 128 + tid];
        lap[tid] = scW1[256 * 128 + tid];
        lw2[tid] = scW2[tid];
    } else if (tid < 192) {
        int j = tid - 128;
        lBs[j] = Bs[s * 64 + j];
        lbp[j] = teW[256 * 64 + j];
    }
    __syncthreads();
    float scb2 = scb2p[0];
    int w = tid >> 6, lane = tid & 63;
    int j = lane;
    float cAs0 = lAs[j], cAs1 = lAs[j + 64];
    float cap0 = lap[j], cap1 = lap[j + 64];
    float cw0 = lw2[j], cw1 = lw2[j + 64];
    float cBs = lBs[j], cbp = lbp[j];
    for (int iter = 0; iter < 16; ++iter) {
        int idx = seg * 64 + iter * 4 + w;
        if (idx >= 511) continue;                  // only last (seg=7,iter=15,w=3) wave
        int t = idx + (idx >= s);
        int e = s * 511 + idx;
        float pd = (float)(s - t) * (1.0f / 512.0f);
        float2 at = *reinterpret_cast<const float2*>(&At2[(size_t)t * 128 + 2 * j]);
        float a0 = cAs0 + at.x + pd * cap0;
        float a1 = cAs1 + at.y + pd * cap1;
        float part = fgelu(a0) * cw0 + fgelu(a1) * cw1;
        for (int off = 32; off; off >>= 1) part += __shfl_xor(part, off);
        float logit = part + scb2;
        float gate = __builtin_amdgcn_rcpf(1.0f + nl[e] * __expf(-logit));
        float f = (cBs + Bt[t * 64 + j] + pd * cbp) * gate;
        out_feat[(size_t)e * 64 + j] = f;
        if (lane == 0) out_gate[e] = gate;
    }
}

extern "C" void kernel_launch(void* const* d_in, const int* in_sizes, int n_in,
                              void* d_out, int out_size, void* d_ws, size_t ws_size,
                              hipStream_t stream) {
    const int*   tok   = (const int*)d_in[0];
    const float* u     = (const float*)d_in[1];
    const float* emb   = (const float*)d_in[2];
    const float* Wqkv  = (const float*)d_in[3];
    const float* bqkv  = (const float*)d_in[4];
    const float* Wo    = (const float*)d_in[5];
    const float* bo    = (const float*)d_in[6];
    const float* ln1g  = (const float*)d_in[7];
    const float* ln1b  = (const float*)d_in[8];
    const float* Wff1  = (const float*)d_in[9];
    const float* bff1  = (const float*)d_in[10];
    const float* Wff2  = (const float*)d_in[11];
    const float* bff2  = (const float*)d_in[12];
    const float* ln2g  = (const float*)d_in[13];
    const float* ln2b  = (const float*)d_in[14];
    const float* nodeW = (const float*)d_in[15];
    const float* nodeb = (const float*)d_in[16];
    const float* scW1  = (const float*)d_in[17];
    const float* scb1  = (const float*)d_in[18];
    const float* scW2  = (const float*)d_in[19];
    const float* scb2  = (const float*)d_in[20];
    const float* teW   = (const float*)d_in[21];
    const float* teb   = (const float*)d_in[22];

    float* out      = (float*)d_out;
    float* out_node = out;                                    // [512,64]
    float* out_feat = out + 512 * 64;                         // [E,64]
    float* out_ei   = out_feat + (size_t)E_EDGES * 64;        // [2,E]
    float* out_gate = out_ei + 2 * (size_t)E_EDGES;           // [E]

    float* ws   = (float*)d_ws;
    float* x    = ws;                                         // 512*128
    float* qkv  = x + 512 * 128;                              // 512*384
    float* o    = qkv + 512 * 384;                            // 512*128
    float* As   = o + 512 * 128;                              // 512*128
    float* At2  = As + 512 * 128;                             // 512*128
    float* Bs   = At2 + 512 * 128;                            // 512*64
    float* Bt   = Bs + 512 * 64;                              // 512*64
    float* nl   = Bt + 512 * 64;                              // E

    k_estatic<<<dim3((E_EDGES + 255) / 256), dim3(256), 0, stream>>>(u, nl, out_ei);
    k_embed<<<dim3(512), dim3(128), 0, stream>>>(tok, emb, x);
    for (int l = 0; l < 2; ++l) {
        k_qkv<<<dim3(128), dim3(384), 0, stream>>>(x, Wqkv + l * 128 * 384, bqkv + l * 384, qkv);
        k_attn<<<dim3(512), dim3(256), 0, stream>>>(qkv, o);
        k_tail<<<dim3(256), dim3(256), 0, stream>>>(o, Wo + l * 128 * 128, bo + l * 128,
                                                    ln1g + l * 128, ln1b + l * 128,
                                                    Wff1 + l * 128 * 512, bff1 + l * 512,
                                                    Wff2 + l * 512 * 128, bff2 + l * 128,
                                                    ln2g + l * 128, ln2b + l * 128, x);
    }
    k_node_pre<<<dim3(128), dim3(448), 0, stream>>>(x, nodeW, nodeb, scW1, scb1, teW, teb,
                                                    out_node, As, At2, Bs, Bt);
    k_edges<<<dim3(512, 8), dim3(256), 0, stream>>>(As, At2, Bs, Bt, scW1, scW2, scb2, teW, nl,
                                                    out_feat, out_gate);
}

// Round 4
// 277.670 us; speedup vs baseline: 1.1885x; 1.0363x over previous
//
#include <hip/hip_runtime.h>
#include <math.h>

#define SS 512
#define DD 128
#define HH 4
#define DHH 32
#define DFF 512
#define E_EDGES 261632   // S*S - S

// exact gelu (backbone)
__device__ __forceinline__ float gelu_f(float v) {
    return 0.5f * v * (1.0f + erff(v * 0.70710678118654752f));
}
// fast gelu (edge kernel): x * sigmoid(1.5957691*(x + 0.044715 x^3))
// exp-arg folded: -(1.5957691*x + 0.07135482*x^3)
__device__ __forceinline__ float fgelu(float x) {
    float x2 = x * x;
    float z = x * fmaf(-0.0713548164f, x2, -1.5957691216f);
    float e = __expf(z);
    return x * __builtin_amdgcn_rcpf(1.0f + e);
}

// ---------------- merged: edge_index + (-log u) + embedding/pos-enc ----------------
__global__ __launch_bounds__(256) void k_pre(const float* __restrict__ u,
                                             float* __restrict__ nl,
                                             float* __restrict__ out_ei,
                                             const int* __restrict__ tok,
                                             const float* __restrict__ emb,
                                             float* __restrict__ x) {
    int b = blockIdx.x;
    if (b < 1022) {                                 // gumbel + edge_index
        int e = b * 256 + threadIdx.x;
        if (e >= E_EDGES) return;
        int s = e / 511;
        int idx = e - s * 511;
        int t = idx + (idx >= s);
        out_ei[e] = (float)s;
        out_ei[E_EDGES + e] = (float)t;
        float uu = fminf(fmaxf(u[e], 1e-8f), 1.0f - 1e-8f);
        nl[e] = -__logf(uu);                        // gate = 1/(1 + nl*exp(-logit))
    } else {                                        // embedding + positional encoding
        int i = (b - 1022) * 256 + threadIdx.x;     // 512*128 elements
        int s = i >> 7, d = i & 127;
        float v = emb[(size_t)tok[s] * DD + d];
        int i2 = (d >> 1) << 1;
        float div = expf(-(float)i2 * (9.210340371976184f / 128.0f));
        float arg = (float)s * div;
        v += (d & 1) ? cosf(arg) : sinf(arg);
        x[i] = v;
    }
}

// ---------------- qkv projection: 2 rows per block ----------------
__global__ __launch_bounds__(384) void k_qkv(const float* __restrict__ x,
                                             const float* __restrict__ W,
                                             const float* __restrict__ b,
                                             float* __restrict__ qkv) {
    __shared__ float xs[2][DD];
    int r0 = blockIdx.x * 2;
    int c = threadIdx.x;
    if (c < 256) xs[c >> 7][c & 127] = x[r0 * DD + c];
    __syncthreads();
    float a0 = 0, a1 = 0;
    for (int d = 0; d < DD; ++d) {
        float w = W[d * 384 + c];
        a0 += xs[0][d] * w; a1 += xs[1][d] * w;
    }
    float bb = b[c];
    qkv[(r0 + 0) * 384 + c] = a0 + bb;
    qkv[(r0 + 1) * 384 + c] = a1 + bb;
}

// ---------------- attention: 2 query rows per block; K staged in LDS once ----------------
__global__ __launch_bounds__(256) void k_attn(const float* __restrict__ qkv,
                                              float* __restrict__ o) {
    int q0 = blockIdx.x * 2, q1 = q0 + 1;
    int tid = threadIdx.x;
    int h = tid >> 6, lane = tid & 63;
    __shared__ float sq[2][DD];
    __shared__ float ps[2][HH][SS];
    __shared__ float tile[64 * 129];
    if (tid < 128) {
        sq[0][tid] = qkv[q0 * 384 + tid];
        sq[1][tid] = qkv[q1 * 384 + tid];
    }
    const float scale = 0.17677669529663687f;       // 1/sqrt(32)
    float sc0[8], sc1[8];
    float m0 = -1e30f, m1 = -1e30f;
    for (int kk = 0; kk < 8; ++kk) {
        __syncthreads();                            // protects tile (and sq on first iter)
        for (int i = tid * 4; i < 64 * 128; i += 1024) {
            int r = i >> 7, c = i & 127;
            const float4 v = *reinterpret_cast<const float4*>(&qkv[(kk * 64 + r) * 384 + 128 + c]);
            tile[r * 129 + c + 0] = v.x;
            tile[r * 129 + c + 1] = v.y;
            tile[r * 129 + c + 2] = v.z;
            tile[r * 129 + c + 3] = v.w;
        }
        __syncthreads();
        float a0 = 0.f, a1 = 0.f;
        #pragma unroll
        for (int d = 0; d < DHH; ++d) {
            float kv = tile[lane * 129 + h * DHH + d];
            a0 += sq[0][h * DHH + d] * kv;
            a1 += sq[1][h * DHH + d] * kv;
        }
        sc0[kk] = a0 * scale; sc1[kk] = a1 * scale;
        m0 = fmaxf(m0, sc0[kk]); m1 = fmaxf(m1, sc1[kk]);
    }
    for (int off = 32; off; off >>= 1) {
        m0 = fmaxf(m0, __shfl_xor(m0, off));
        m1 = fmaxf(m1, __shfl_xor(m1, off));
    }
    float s0 = 0.f, s1 = 0.f;
    for (int kk = 0; kk < 8; ++kk) {
        sc0[kk] = __expf(sc0[kk] - m0); s0 += sc0[kk];
        sc1[kk] = __expf(sc1[kk] - m1); s1 += sc1[kk];
    }
    for (int off = 32; off; off >>= 1) {
        s0 += __shfl_xor(s0, off);
        s1 += __shfl_xor(s1, off);
    }
    float i0 = 1.0f / s0, i1 = 1.0f / s1;
    for (int kk = 0; kk < 8; ++kk) {
        ps[0][h][kk * 64 + lane] = sc0[kk] * i0;
        ps[1][h][kk * 64 + lane] = sc1[kk] * i1;
    }
    __syncthreads();
    int d = lane & 31, hh2 = lane >> 5;
    float a0 = 0.f, a1 = 0.f;
    for (int i = 0; i < 256; ++i) {
        int ki = hh2 * 256 + i;
        float v = qkv[ki * 384 + 256 + h * DHH + d];
        a0 += ps[0][h][ki] * v;
        a1 += ps[1][h][ki] * v;
    }
    a0 += __shfl_down(a0, 32);
    a1 += __shfl_down(a1, 32);
    if (lane < 32) {
        o[q0 * DD + h * DHH + d] = a0;
        o[q1 * DD + h * DHH + d] = a1;
    }
}

// ---------------- fused layer tail: proj+LN1 -> FFN1 -> FFN2+LN2 (2 rows/block) ----------------
__global__ __launch_bounds__(256) void k_tail(const float* __restrict__ o,
                                              const float* __restrict__ Wo,
                                              const float* __restrict__ bo,
                                              const float* __restrict__ g1,
                                              const float* __restrict__ b1,
                                              const float* __restrict__ W1,
                                              const float* __restrict__ bf1,
                                              const float* __restrict__ W2,
                                              const float* __restrict__ bf2,
                                              const float* __restrict__ g2,
                                              const float* __restrict__ b2,
                                              float* __restrict__ x) {
    int r0 = blockIdx.x * 2;
    int tid = threadIdx.x;
    int grp = tid >> 7, c = tid & 127;
    int wig = (tid >> 6) & 1;
    __shared__ float osr[2][DD];
    __shared__ float x1[2][DD];
    __shared__ float hh[2][DFF];
    __shared__ float red[2][2];
    osr[grp][c] = o[(r0 + grp) * DD + c];
    float xres = x[(r0 + grp) * DD + c];
    __syncthreads();
    float acc = 0.f;
    for (int d = 0; d < DD; ++d) acc += osr[grp][d] * Wo[d * DD + c];
    float val = xres + acc + bo[c];
    float sum = val;
    for (int off = 32; off; off >>= 1) sum += __shfl_xor(sum, off);
    if ((tid & 63) == 0) red[grp][wig] = sum;
    __syncthreads();
    float mean = (red[grp][0] + red[grp][1]) * (1.0f / 128.0f);
    float dv = val - mean;
    float sq = dv * dv;
    for (int off = 32; off; off >>= 1) sq += __shfl_xor(sq, off);
    __syncthreads();
    if ((tid & 63) == 0) red[grp][wig] = sq;
    __syncthreads();
    float var = (red[grp][0] + red[grp][1]) * (1.0f / 128.0f);
    float xv = dv * rsqrtf(var + 1e-5f) * g1[c] + b1[c];
    x1[grp][c] = xv;
    __syncthreads();
    {
        int c0 = tid, c1 = tid + 256;
        float s00 = 0, s01 = 0, s10 = 0, s11 = 0;
        for (int d = 0; d < DD; ++d) {
            float xa = x1[0][d], xb = x1[1][d];
            float w0 = W1[d * DFF + c0], w1 = W1[d * DFF + c1];
            s00 = fmaf(xa, w0, s00); s10 = fmaf(xb, w0, s10);
            s01 = fmaf(xa, w1, s01); s11 = fmaf(xb, w1, s11);
        }
        hh[0][c0] = gelu_f(s00 + bf1[c0]);
        hh[1][c0] = gelu_f(s10 + bf1[c0]);
        hh[0][c1] = gelu_f(s01 + bf1[c1]);
        hh[1][c1] = gelu_f(s11 + bf1[c1]);
    }
    __syncthreads();
    float acc2 = 0.f;
    for (int d = 0; d < DFF; ++d) acc2 += hh[grp][d] * W2[d * DD + c];
    float val2 = x1[grp][c] + acc2 + bf2[c];
    float sum2 = val2;
    for (int off = 32; off; off >>= 1) sum2 += __shfl_xor(sum2, off);
    if ((tid & 63) == 0) red[grp][wig] = sum2;
    __syncthreads();
    float mean2 = (red[grp][0] + red[grp][1]) * (1.0f / 128.0f);
    float dv2 = val2 - mean2;
    float sq2 = dv2 * dv2;
    for (int off = 32; off; off >>= 1) sq2 += __shfl_xor(sq2, off);
    __syncthreads();
    if ((tid & 63) == 0) red[grp][wig] = sq2;
    __syncthreads();
    float var2 = (red[grp][0] + red[grp][1]) * (1.0f / 128.0f);
    x[(r0 + grp) * DD + c] = dv2 * rsqrtf(var2 + 1e-5f) * g2[c] + b2[c];
}

// ---------------- node features + per-node edge-MLP partials ----------------
// Atp[row*128 + jj*8 + k*2 + h] = (x@scW1_tgt)[row][jj+16k+64h],  jj<16,k<4,h<2
// Btp[row*64  + jj*4 + k]       = (x@teW_tgt)[row][jj+16k]
__global__ __launch_bounds__(448) void k_node_pre(const float* __restrict__ x,
                                                  const float* __restrict__ nodeW,
                                                  const float* __restrict__ nodeb,
                                                  const float* __restrict__ scW1,
                                                  const float* __restrict__ scb1,
                                                  const float* __restrict__ teW,
                                                  const float* __restrict__ teb,
                                                  float* __restrict__ out_node,
                                                  float* __restrict__ As,
                                                  float* __restrict__ Atp,
                                                  float* __restrict__ Bs,
                                                  float* __restrict__ Btp) {
    __shared__ float xs[4][DD];
    int r0 = blockIdx.x * 4;
    for (int i = threadIdx.x; i < 4 * DD; i += 448)
        xs[i >> 7][i & 127] = x[(r0 + (i >> 7)) * DD + (i & 127)];
    __syncthreads();
    int c = threadIdx.x;
    const float* wp;
    int ldw;
    if (c < 64)       { wp = nodeW + c;                    ldw = 64;  }
    else if (c < 192) { wp = scW1 + (c - 64);              ldw = 128; }
    else if (c < 320) { wp = scW1 + 128 * 128 + (c - 192); ldw = 128; }
    else if (c < 384) { wp = teW + (c - 320);              ldw = 64;  }
    else              { wp = teW + 128 * 64 + (c - 384);   ldw = 64;  }
    float a[4] = {0, 0, 0, 0};
    for (int d = 0; d < DD; ++d) {
        float w = wp[d * ldw];
        a[0] += xs[0][d] * w; a[1] += xs[1][d] * w;
        a[2] += xs[2][d] * w; a[3] += xs[3][d] * w;
    }
    #pragma unroll
    for (int r = 0; r < 4; ++r) {
        int row = r0 + r;
        float v = a[r];
        if (c < 64)       out_node[row * 64 + c] = v + nodeb[c];
        else if (c < 192) As[row * 128 + (c - 64)] = v + scb1[c - 64];
        else if (c < 320) {
            int j0 = c - 192;                       // 0..127
            int hhi = j0 >> 6, rem = j0 & 63;
            int jj = rem & 15, k = rem >> 4;
            Atp[row * 128 + jj * 8 + k * 2 + hhi] = v;
        }
        else if (c < 384) Bs[row * 64 + (c - 320)] = v + teb[c - 320];
        else {
            int jf = c - 384;                       // 0..63
            int jj = jf & 15, k = jf >> 4;
            Btp[row * 64 + jj * 4 + k] = v;
        }
    }
}

// ---------------- edge kernel: 4 edges per wave (16 lanes each) ----------------
__global__ __launch_bounds__(256) void k_edges(const float* __restrict__ As,
                                               const float* __restrict__ Atp,
                                               const float* __restrict__ Bs,
                                               const float* __restrict__ Btp,
                                               const float* __restrict__ scW1,
                                               const float* __restrict__ scW2,
                                               const float* __restrict__ scb2p,
                                               const float* __restrict__ teW,
                                               const float* __restrict__ nl,
                                               float* __restrict__ out_feat,
                                               float* __restrict__ out_gate) {
    int s = blockIdx.x;
    int seg = blockIdx.y;                           // 0..1
    __shared__ float lAs[128], lap[128], lw2[128], lBs[64], lbp[64];
    int tid = threadIdx.x;
    if (tid < 128) {
        lAs[tid] = As[s * 128 + tid];
        lap[tid] = scW1[256 * 128 + tid];
        lw2[tid] = scW2[tid];
    } else if (tid < 192) {
        int j = tid - 128;
        lBs[j] = Bs[s * 64 + j];
        lbp[j] = teW[256 * 64 + j];
    }
    __syncthreads();
    int w = tid >> 6, lane = tid & 63;
    int g = lane >> 4, jj = lane & 15;
    // per-lane register preload: features j = jj + 16k (k=0..3), halves j and j+64
    float rAs[8], rap[8], rw2[8], rBs[4], rbp[4];
    #pragma unroll
    for (int k = 0; k < 4; ++k) {
        int j = jj + 16 * k;
        rAs[2 * k] = lAs[j]; rAs[2 * k + 1] = lAs[j + 64];
        rap[2 * k] = lap[j]; rap[2 * k + 1] = lap[j + 64];
        rw2[2 * k] = lw2[j]; rw2[2 * k + 1] = lw2[j + 64];
        rBs[k] = lBs[j]; rbp[k] = lbp[j];
    }
    float scb2 = scb2p[0];
    for (int iter = 0; iter < 16; ++iter) {
        int idx = seg * 256 + w * 64 + iter * 4 + g;
        if (idx >= 511) continue;                   // uniform per 16-lane group
        int t = idx + (idx >= s);
        int e = s * 511 + idx;
        float pd = (float)(s - t) * (1.0f / 512.0f);
        const float4* ap = reinterpret_cast<const float4*>(&Atp[(size_t)t * 128 + jj * 8]);
        float4 at0 = ap[0];                         // (k0,h0)(k0,h1)(k1,h0)(k1,h1)
        float4 at1 = ap[1];                         // (k2,h0)(k2,h1)(k3,h0)(k3,h1)
        float part;
        float a;
        a = fmaf(pd, rap[0], rAs[0] + at0.x); part  = fgelu(a) * rw2[0];
        a = fmaf(pd, rap[1], rAs[1] + at0.y); part += fgelu(a) * rw2[1];
        a = fmaf(pd, rap[2], rAs[2] + at0.z); part += fgelu(a) * rw2[2];
        a = fmaf(pd, rap[3], rAs[3] + at0.w); part += fgelu(a) * rw2[3];
        a = fmaf(pd, rap[4], rAs[4] + at1.x); part += fgelu(a) * rw2[4];
        a = fmaf(pd, rap[5], rAs[5] + at1.y); part += fgelu(a) * rw2[5];
        a = fmaf(pd, rap[6], rAs[6] + at1.z); part += fgelu(a) * rw2[6];
        a = fmaf(pd, rap[7], rAs[7] + at1.w); part += fgelu(a) * rw2[7];
        part += __shfl_xor(part, 1);                // reduce within 16-lane group
        part += __shfl_xor(part, 2);
        part += __shfl_xor(part, 4);
        part += __shfl_xor(part, 8);
        float logit = part + scb2;
        float gate = __builtin_amdgcn_rcpf(1.0f + nl[e] * __expf(-logit));
        float4 bt = *reinterpret_cast<const float4*>(&Btp[(size_t)t * 64 + jj * 4]);
        float f0 = fmaf(pd, rbp[0], rBs[0] + bt.x) * gate;
        float f1 = fmaf(pd, rbp[1], rBs[1] + bt.y) * gate;
        float f2 = fmaf(pd, rbp[2], rBs[2] + bt.z) * gate;
        float f3 = fmaf(pd, rbp[3], rBs[3] + bt.w) * gate;
        size_t base = (size_t)e * 64 + jj;
        out_feat[base + 0]  = f0;
        out_feat[base + 16] = f1;
        out_feat[base + 32] = f2;
        out_feat[base + 48] = f3;
        if (jj == 0) out_gate[e] = gate;
    }
}

extern "C" void kernel_launch(void* const* d_in, const int* in_sizes, int n_in,
                              void* d_out, int out_size, void* d_ws, size_t ws_size,
                              hipStream_t stream) {
    const int*   tok   = (const int*)d_in[0];
    const float* u     = (const float*)d_in[1];
    const float* emb   = (const float*)d_in[2];
    const float* Wqkv  = (const float*)d_in[3];
    const float* bqkv  = (const float*)d_in[4];
    const float* Wo    = (const float*)d_in[5];
    const float* bo    = (const float*)d_in[6];
    const float* ln1g  = (const float*)d_in[7];
    const float* ln1b  = (const float*)d_in[8];
    const float* Wff1  = (const float*)d_in[9];
    const float* bff1  = (const float*)d_in[10];
    const float* Wff2  = (const float*)d_in[11];
    const float* bff2  = (const float*)d_in[12];
    const float* ln2g  = (const float*)d_in[13];
    const float* ln2b  = (const float*)d_in[14];
    const float* nodeW = (const float*)d_in[15];
    const float* nodeb = (const float*)d_in[16];
    const float* scW1  = (const float*)d_in[17];
    const float* scb1  = (const float*)d_in[18];
    const float* scW2  = (const float*)d_in[19];
    const float* scb2  = (const float*)d_in[20];
    const float* teW   = (const float*)d_in[21];
    const float* teb   = (const float*)d_in[22];

    float* out      = (float*)d_out;
    float* out_node = out;                                    // [512,64]
    float* out_feat = out + 512 * 64;                         // [E,64]
    float* out_ei   = out_feat + (size_t)E_EDGES * 64;        // [2,E]
    float* out_gate = out_ei + 2 * (size_t)E_EDGES;           // [E]

    float* ws   = (float*)d_ws;
    float* x    = ws;                                         // 512*128
    float* qkv  = x + 512 * 128;                              // 512*384
    float* o    = qkv + 512 * 384;                            // 512*128
    float* As   = o + 512 * 128;                              // 512*128
    float* Atp  = As + 512 * 128;                             // 512*128
    float* Bs   = Atp + 512 * 128;                            // 512*64
    float* Btp  = Bs + 512 * 64;                              // 512*64
    float* nl   = Btp + 512 * 64;                             // E

    k_pre<<<dim3(1278), dim3(256), 0, stream>>>(u, nl, out_ei, tok, emb, x);
    for (int l = 0; l < 2; ++l) {
        k_qkv<<<dim3(256), dim3(384), 0, stream>>>(x, Wqkv + l * 128 * 384, bqkv + l * 384, qkv);
        k_attn<<<dim3(256), dim3(256), 0, stream>>>(qkv, o);
        k_tail<<<dim3(256), dim3(256), 0, stream>>>(o, Wo + l * 128 * 128, bo + l * 128,
                                                    ln1g + l * 128, ln1b + l * 128,
                                                    Wff1 + l * 128 * 512, bff1 + l * 512,
                                                    Wff2 + l * 512 * 128, bff2 + l * 128,
                                                    ln2g + l * 128, ln2b + l * 128, x);
    }
    k_node_pre<<<dim3(128), dim3(448), 0, stream>>>(x, nodeW, nodeb, scW1, scb1, teW, teb,
                                                    out_node, As, Atp, Bs, Btp);
    k_edges<<<dim3(512, 2), dim3(256), 0, stream>>>(As, Atp, Bs, Btp, scW1, scW2, scb2, teW, nl,
                                                    out_feat, out_gate);
}